// Round 6
// baseline (148.268 us; speedup 1.0000x reference)
//
#include <hip/hip_runtime.h>
#include <hip/hip_bf16.h>

typedef __attribute__((ext_vector_type(8))) short short8;
typedef __attribute__((ext_vector_type(4))) float float4v;

typedef __attribute__((address_space(3))) unsigned int lds_u32;
typedef __attribute__((address_space(1))) const unsigned int glb_u32;

__device__ __forceinline__ unsigned short f2bf(float f) {
    // round-to-nearest-even fp32 -> bf16
    unsigned int u = __builtin_bit_cast(unsigned int, f);
    unsigned int lsb = (u >> 16) & 1u;
    u += 0x7fffu + lsb;
    return (unsigned short)(u >> 16);
}

__device__ __forceinline__ unsigned int pack2(float f0, float f1) {
    // round-half-up fp32x2 -> packed bf16x2
    unsigned int u0 = __builtin_bit_cast(unsigned int, f0) + 0x8000u;
    unsigned int u1 = __builtin_bit_cast(unsigned int, f1) + 0x8000u;
    return (u0 >> 16) | (u1 & 0xffff0000u);
}

// ---------------------------------------------------------------------------
// prep (merged, one dispatch):
// blocks [0,512):    LayerNorm + [wa|wb] projection via MFMA. n = b>>1,
//                    s-half = (b&1)*32; 128 thr = 2 waves, wave w: 16 s-rows.
//                    b_out stored with XOR-swizzled k-octets (see R5) so
//                    fused's linear global_load_lds yields conflict-free
//                    ds_read_b128 b-fragments.
// blocks [512,1024): wo [1024][64] f32 -> woT [p][kk] bf16, kk = k*32+h.
// ---------------------------------------------------------------------------
__global__ __launch_bounds__(128) void prep(
    const float* __restrict__ msa, const float* __restrict__ ln_w,
    const float* __restrict__ ln_b, const float* __restrict__ wa,
    const float* __restrict__ ba, const float* __restrict__ wb,
    const float* __restrict__ bb, const float* __restrict__ wo,
    unsigned short* __restrict__ a_out, unsigned short* __restrict__ b_out,
    unsigned short* __restrict__ woT)
{
    const int b = blockIdx.x;
    if (b >= 512) {                       // ---- woT transpose/convert ----
        const int idx = (b - 512) * 128 + threadIdx.x;
        const int hk = idx >> 6, p = idx & 63;
        const int h = hk >> 5, k = hk & 31;
        woT[(size_t)p * 1024 + k * 32 + h] = f2bf(wo[idx]);
        return;
    }

    // ---- LN + projections ----
    __shared__ __align__(16) unsigned short xn[2][16 * 72];
    const int n = b >> 1;
    const int w = threadIdx.x >> 6;
    const int lane = threadIdx.x & 63;
    const int s0 = (b & 1) * 32 + w * 16;
    const int sl = lane >> 2, dg = lane & 3;
    const int lm = lane & 15, q = lane >> 4;

    const float* __restrict__ row = msa + ((size_t)((s0 + sl) * 256 + n)) * 64;
    float4 x[4];
    #pragma unroll
    for (int ii = 0; ii < 4; ++ii) x[ii] = *(const float4*)(row + ii * 16 + dg * 4);

    float s = 0.f;
    #pragma unroll
    for (int ii = 0; ii < 4; ++ii) s += (x[ii].x + x[ii].y) + (x[ii].z + x[ii].w);
    s += __shfl_xor(s, 1, 4);
    s += __shfl_xor(s, 2, 4);
    const float mu = s * (1.f / 64.f);

    float v = 0.f;
    #pragma unroll
    for (int ii = 0; ii < 4; ++ii) {
        float a0 = x[ii].x - mu, a1 = x[ii].y - mu, a2 = x[ii].z - mu, a3 = x[ii].w - mu;
        v += (a0 * a0 + a1 * a1) + (a2 * a2 + a3 * a3);
    }
    v += __shfl_xor(v, 1, 4);
    v += __shfl_xor(v, 2, 4);
    const float rs = rsqrtf(v * (1.f / 64.f) + 1e-5f);

    #pragma unroll
    for (int ii = 0; ii < 4; ++ii) {
        const float4 lw = *(const float4*)(ln_w + ii * 16 + dg * 4);
        const float4 lb = *(const float4*)(ln_b + ii * 16 + dg * 4);
        uint2 pk;
        pk.x = pack2((x[ii].x - mu) * rs * lw.x + lb.x, (x[ii].y - mu) * rs * lw.y + lb.y);
        pk.y = pack2((x[ii].z - mu) * rs * lw.z + lb.z, (x[ii].w - mu) * rs * lw.w + lb.w);
        *(uint2*)(&xn[w][sl * 72 + ii * 16 + dg * 4]) = pk;
    }
    __syncthreads();

    short8 afr[2];
    #pragma unroll
    for (int ks = 0; ks < 2; ++ks)
        afr[ks] = *(const short8*)(&xn[w][lm * 72 + ks * 32 + q * 8]);

    float4v acc[4];
    #pragma unroll
    for (int c = 0; c < 4; ++c) acc[c] = (float4v){0.f, 0.f, 0.f, 0.f};
    #pragma unroll
    for (int c = 0; c < 4; ++c) {
        const int hp = c * 16 + lm;
        const float* __restrict__ wsrc = (hp < 32) ? (wa + hp) : (wb + hp - 32);
        #pragma unroll
        for (int ks = 0; ks < 2; ++ks) {
            short8 bfr;
            #pragma unroll
            for (int j = 0; j < 8; ++j)
                bfr[j] = (short)f2bf(wsrc[(ks * 32 + q * 8 + j) * 32]);
            acc[c] = __builtin_amdgcn_mfma_f32_16x16x32_bf16(afr[ks], bfr, acc[c], 0, 0, 0);
        }
    }

    #pragma unroll
    for (int c = 0; c < 4; ++c) {
        const int hp = c * 16 + lm;
        const float bias = (hp < 32) ? ba[hp] : bb[hp - 32];
        const float scale = (hp < 32) ? (1.f / 64.f) : 1.f;  // fold 1/S into a
        uint2 pk;
        pk.x = pack2((acc[c][0] + bias) * scale, (acc[c][1] + bias) * scale);
        pk.y = pack2((acc[c][2] + bias) * scale, (acc[c][3] + bias) * scale);
        const int sbase = s0 + q * 4;
        if (hp < 32) {
            *(uint2*)(a_out + ((size_t)(n * 32 + hp)) * 64 + sbase) = pk;
        } else {
            const int R = n * 32 + (hp - 32);
            const int o = sbase >> 3;
            const int phys = (R << 6) + (((o ^ (R & 7)) << 3) | (sbase & 7));
            *(uint2*)(b_out + phys) = pk;
        }
    }
}

// ---------------------------------------------------------------------------
// fused_opm v6: 1024 blocks x 256 thr (4 waves); block b: bi = b>>4, 4 bj
// tiles. v6 change: LDS cut 73.5 -> 49.4 KB for 3 blocks/CU (12 waves/CU,
// +50% latency hiding; v5 was pinned at 2 blocks by LDS):
//   - ldsB single-buffered (16 KB): fill(t+1) issues after bar1(t) and
//     overlaps stage-2(t); drained by bar2 before stage-1(t+1) reads.
//   - ldsM compact (pair stride 1032, k-stride 32 = 33 KB) with 4-dword XOR
//     swizzle on h-chunks by (k&3): b128 reads 2-way (free), uint2 writes
//     4-way (~1.6x on 16 instr/tile/wave — negligible).
// Needs >=768 blocks to fill 3 slots -> grid 1024x4 (R3's 1024x4 regression
// was at fixed 2-slot occupancy; the +slot is the point here).
// ---------------------------------------------------------------------------
__global__ __launch_bounds__(256, 3) void fused_opm(
    const unsigned short* __restrict__ a_b, const unsigned short* __restrict__ b_swz,
    const unsigned short* __restrict__ woT, const float* __restrict__ bo,
    float* __restrict__ out)
{
    __shared__ __align__(16) unsigned short ldsB[128 * 64];   // swizzled b-tile
    __shared__ __align__(16) unsigned short ldsM[16 * 1032];  // compact, XOR-swizzled

    const int b = blockIdx.x;
    const int bi = b >> 4;
    const int bj0 = (b & 15) << 2;
    const int w = threadIdx.x >> 6;
    const int lane = threadIdx.x & 63;
    const int lm = lane & 15, q = lane >> 4;

    // async fill: copy 16 KB b-tile bjx (linear, pre-swizzled in prep)
    auto fill = [&](int bjx) {
        #pragma unroll
        for (int li = 0; li < 4; ++li) {
            const int chunk = w * 4 + li;                       // 16 x 1 KB chunks
            const unsigned short* g = b_swz + (size_t)bjx * 8192 + chunk * 512 + lane * 8;
            __builtin_amdgcn_global_load_lds((glb_u32*)g,
                (lds_u32*)(&ldsB[chunk * 512]), 16, 0, 0);
        }
    };

    fill(bj0);

    // hoisted a-fragments: rows (i=bi*4+w, h=r*16+lm)
    short8 af[2][2];
    #pragma unroll
    for (int r = 0; r < 2; ++r)
        #pragma unroll
        for (int ks = 0; ks < 2; ++ks)
            af[r][ks] = *(const short8*)(a_b + ((size_t)(bi * 128 + w * 32 + r * 16 + lm)) * 64 + ks * 32 + q * 8);

    // register-resident woT: rows p = w*16+lm
    short8 wf[32];
    #pragma unroll
    for (int ks = 0; ks < 32; ++ks)
        wf[ks] = *(const short8*)(woT + ((size_t)(w * 16 + lm)) * 1024 + ks * 32 + q * 8);

    const float4 bo4 = *(const float4*)(bo + w * 16 + q * 4);
    const int i = bi * 4 + (lm >> 2);   // stage-2 pair = lm
    const int jb = lm & 3;

    __syncthreads();   // fill(bj0) drained (vmcnt at barrier)

    for (int t = 0; t < 4; ++t) {
        const int bj = bj0 + t;

        // ---- stage 1: outer tile -> ldsM (b-frags from ldsB, swizzled) ----
        #pragma unroll
        for (int half = 0; half < 2; ++half) {
            short8 bf[4][2];
            #pragma unroll
            for (int c2 = 0; c2 < 4; ++c2)
                #pragma unroll
                for (int ks = 0; ks < 2; ++ks) {
                    const int rrow = (half * 4 + c2) * 16 + lm;
                    const int o = ks * 4 + q;                   // k-octet
                    bf[c2][ks] = *(const short8*)(&ldsB[(rrow << 6) + ((o ^ (rrow & 7)) << 3)]);
                }
            float4v acc1[2][4];
            #pragma unroll
            for (int r = 0; r < 2; ++r)
                #pragma unroll
                for (int c2 = 0; c2 < 4; ++c2) acc1[r][c2] = (float4v){0.f, 0.f, 0.f, 0.f};
            #pragma unroll
            for (int c2 = 0; c2 < 4; ++c2)
                #pragma unroll
                for (int ks = 0; ks < 2; ++ks)
                    #pragma unroll
                    for (int r = 0; r < 2; ++r)
                        acc1[r][c2] = __builtin_amdgcn_mfma_f32_16x16x32_bf16(af[r][ks], bf[c2][ks], acc1[r][c2], 0, 0, 0);

            // C: row = w*32+r*16+q*4+e -> (i_loc=w, h), col = c*16+lm -> (j_loc=c>>1, k)
            // ldsM phys: pair*1032 + k*32 + (h0 ^ ((k&3)<<3))
            #pragma unroll
            for (int r = 0; r < 2; ++r)
                #pragma unroll
                for (int c2 = 0; c2 < 4; ++c2) {
                    const int c = half * 4 + c2;
                    const int pair = w * 4 + (c >> 1);
                    const int k = ((c & 1) << 4) + lm;
                    const int h0 = r * 16 + q * 4;
                    uint2 pk;
                    pk.x = pack2(acc1[r][c2][0], acc1[r][c2][1]);
                    pk.y = pack2(acc1[r][c2][2], acc1[r][c2][3]);
                    *(uint2*)(ldsM + pair * 1032 + k * 32 + (h0 ^ ((k & 3) << 3))) = pk;
                }
        }
        __syncthreads();   // bar1: M ready; all ldsB reads of tile t done

        // refill ldsB for tile t+1 (async; overlaps stage 2; drains at bar2)
        if (t < 3) fill(bj0 + t + 1);

        // ---- stage 2: out[p][pair] = woT[p][:] . M[pair][:], dual chains ----
        float4v acc2a = (float4v){0.f, 0.f, 0.f, 0.f};
        float4v acc2b = (float4v){0.f, 0.f, 0.f, 0.f};
        #pragma unroll
        for (int ks = 0; ks < 16; ++ks) {
            const int k0 = 2 * ks, k1 = 2 * ks + 1;
            const short8 mf0 = *(const short8*)(ldsM + lm * 1032 + k0 * 32 + ((q ^ (k0 & 3)) << 3));
            const short8 mf1 = *(const short8*)(ldsM + lm * 1032 + k1 * 32 + ((q ^ (k1 & 3)) << 3));
            acc2a = __builtin_amdgcn_mfma_f32_16x16x32_bf16(wf[k0], mf0, acc2a, 0, 0, 0);
            acc2b = __builtin_amdgcn_mfma_f32_16x16x32_bf16(wf[k1], mf1, acc2b, 0, 0, 0);
        }

        const int j = bj * 4 + jb;
        float4 o;
        o.x = acc2a[0] + acc2b[0] + bo4.x;
        o.y = acc2a[1] + acc2b[1] + bo4.y;
        o.z = acc2a[2] + acc2b[2] + bo4.z;
        o.w = acc2a[3] + acc2b[3] + bo4.w;
        *(float4*)(out + ((size_t)(i * 256 + j)) * 64 + w * 16 + q * 4) = o;
        __syncthreads();   // bar2: ldsM reads done + fill drained
    }
}

// ---------------------------------------------------------------------------
extern "C" void kernel_launch(void* const* d_in, const int* in_sizes, int n_in,
                              void* d_out, int out_size, void* d_ws, size_t ws_size,
                              hipStream_t stream) {
    const float* msa  = (const float*)d_in[0];
    const float* ln_w = (const float*)d_in[1];
    const float* ln_b = (const float*)d_in[2];
    const float* wa   = (const float*)d_in[3];
    const float* ba   = (const float*)d_in[4];
    const float* wb   = (const float*)d_in[5];
    const float* bb   = (const float*)d_in[6];
    const float* wo   = (const float*)d_in[7];
    const float* bo   = (const float*)d_in[8];
    float* out = (float*)d_out;

    // workspace (bf16): a (1 MB) | b (1 MB, octet-swizzled) | woT (128 KB)
    unsigned short* a_ws = (unsigned short*)d_ws;
    unsigned short* b_ws = a_ws + 256 * 32 * 64;
    unsigned short* woT  = b_ws + 256 * 32 * 64;

    prep<<<1024, 128, 0, stream>>>(msa, ln_w, ln_b, wa, ba, wb, bb, wo, a_ws, b_ws, woT);
    fused_opm<<<1024, 256, 0, stream>>>(a_ws, b_ws, woT, bo, out);
}

// Round 7
// 105.044 us; speedup vs baseline: 1.4115x; 1.4115x over previous
//
#include <hip/hip_runtime.h>
#include <hip/hip_bf16.h>

typedef __attribute__((ext_vector_type(8))) short short8;
typedef __attribute__((ext_vector_type(4))) float float4v;

typedef __attribute__((address_space(3))) unsigned int lds_u32;
typedef __attribute__((address_space(1))) const unsigned int glb_u32;

__device__ __forceinline__ unsigned short f2bf(float f) {
    // round-to-nearest-even fp32 -> bf16
    unsigned int u = __builtin_bit_cast(unsigned int, f);
    unsigned int lsb = (u >> 16) & 1u;
    u += 0x7fffu + lsb;
    return (unsigned short)(u >> 16);
}

__device__ __forceinline__ unsigned int pack2(float f0, float f1) {
    // round-half-up fp32x2 -> packed bf16x2
    unsigned int u0 = __builtin_bit_cast(unsigned int, f0) + 0x8000u;
    unsigned int u1 = __builtin_bit_cast(unsigned int, f1) + 0x8000u;
    return (u0 >> 16) | (u1 & 0xffff0000u);
}

// ---------------------------------------------------------------------------
// prep (unchanged from R5 — proven): LN + projections (MFMA) and woT build.
// b_out stored with XOR-swizzled k-octets so fused's linear global_load_lds
// yields conflict-free ds_read_b128 b-fragments.
// ---------------------------------------------------------------------------
__global__ __launch_bounds__(128) void prep(
    const float* __restrict__ msa, const float* __restrict__ ln_w,
    const float* __restrict__ ln_b, const float* __restrict__ wa,
    const float* __restrict__ ba, const float* __restrict__ wb,
    const float* __restrict__ bb, const float* __restrict__ wo,
    unsigned short* __restrict__ a_out, unsigned short* __restrict__ b_out,
    unsigned short* __restrict__ woT)
{
    const int b = blockIdx.x;
    if (b >= 512) {                       // ---- woT transpose/convert ----
        const int idx = (b - 512) * 128 + threadIdx.x;
        const int hk = idx >> 6, p = idx & 63;
        const int h = hk >> 5, k = hk & 31;
        woT[(size_t)p * 1024 + k * 32 + h] = f2bf(wo[idx]);
        return;
    }

    __shared__ __align__(16) unsigned short xn[2][16 * 72];
    const int n = b >> 1;
    const int w = threadIdx.x >> 6;
    const int lane = threadIdx.x & 63;
    const int s0 = (b & 1) * 32 + w * 16;
    const int sl = lane >> 2, dg = lane & 3;
    const int lm = lane & 15, q = lane >> 4;

    const float* __restrict__ row = msa + ((size_t)((s0 + sl) * 256 + n)) * 64;
    float4 x[4];
    #pragma unroll
    for (int ii = 0; ii < 4; ++ii) x[ii] = *(const float4*)(row + ii * 16 + dg * 4);

    float s = 0.f;
    #pragma unroll
    for (int ii = 0; ii < 4; ++ii) s += (x[ii].x + x[ii].y) + (x[ii].z + x[ii].w);
    s += __shfl_xor(s, 1, 4);
    s += __shfl_xor(s, 2, 4);
    const float mu = s * (1.f / 64.f);

    float v = 0.f;
    #pragma unroll
    for (int ii = 0; ii < 4; ++ii) {
        float a0 = x[ii].x - mu, a1 = x[ii].y - mu, a2 = x[ii].z - mu, a3 = x[ii].w - mu;
        v += (a0 * a0 + a1 * a1) + (a2 * a2 + a3 * a3);
    }
    v += __shfl_xor(v, 1, 4);
    v += __shfl_xor(v, 2, 4);
    const float rs = rsqrtf(v * (1.f / 64.f) + 1e-5f);

    #pragma unroll
    for (int ii = 0; ii < 4; ++ii) {
        const float4 lw = *(const float4*)(ln_w + ii * 16 + dg * 4);
        const float4 lb = *(const float4*)(ln_b + ii * 16 + dg * 4);
        uint2 pk;
        pk.x = pack2((x[ii].x - mu) * rs * lw.x + lb.x, (x[ii].y - mu) * rs * lw.y + lb.y);
        pk.y = pack2((x[ii].z - mu) * rs * lw.z + lb.z, (x[ii].w - mu) * rs * lw.w + lb.w);
        *(uint2*)(&xn[w][sl * 72 + ii * 16 + dg * 4]) = pk;
    }
    __syncthreads();

    short8 afr[2];
    #pragma unroll
    for (int ks = 0; ks < 2; ++ks)
        afr[ks] = *(const short8*)(&xn[w][lm * 72 + ks * 32 + q * 8]);

    float4v acc[4];
    #pragma unroll
    for (int c = 0; c < 4; ++c) acc[c] = (float4v){0.f, 0.f, 0.f, 0.f};
    #pragma unroll
    for (int c = 0; c < 4; ++c) {
        const int hp = c * 16 + lm;
        const float* __restrict__ wsrc = (hp < 32) ? (wa + hp) : (wb + hp - 32);
        #pragma unroll
        for (int ks = 0; ks < 2; ++ks) {
            short8 bfr;
            #pragma unroll
            for (int j = 0; j < 8; ++j)
                bfr[j] = (short)f2bf(wsrc[(ks * 32 + q * 8 + j) * 32]);
            acc[c] = __builtin_amdgcn_mfma_f32_16x16x32_bf16(afr[ks], bfr, acc[c], 0, 0, 0);
        }
    }

    #pragma unroll
    for (int c = 0; c < 4; ++c) {
        const int hp = c * 16 + lm;
        const float bias = (hp < 32) ? ba[hp] : bb[hp - 32];
        const float scale = (hp < 32) ? (1.f / 64.f) : 1.f;  // fold 1/S into a
        uint2 pk;
        pk.x = pack2((acc[c][0] + bias) * scale, (acc[c][1] + bias) * scale);
        pk.y = pack2((acc[c][2] + bias) * scale, (acc[c][3] + bias) * scale);
        const int sbase = s0 + q * 4;
        if (hp < 32) {
            *(uint2*)(a_out + ((size_t)(n * 32 + hp)) * 64 + sbase) = pk;
        } else {
            const int R = n * 32 + (hp - 32);
            const int o = sbase >> 3;
            const int phys = (R << 6) + (((o ^ (R & 7)) << 3) | (sbase & 7));
            *(uint2*)(b_out + phys) = pk;
        }
    }
}

// ---------------------------------------------------------------------------
// fused_opm v7: producer/consumer wave specialization.
// 256 blocks x 512 thr (8 waves), 1 block/CU (LDS 111.5 KB). bi = b>>2,
// 16 bj tiles per block.
//   waves 0-3 (producers): stage 1 only — per tile, rows [w*32,w*32+32) x
//     128 cols (32 MFMAs), b-frags from double-buffered ldsB (pre-swizzled),
//     C packed bf16 to double-buffered ldsM (v5-proven pair-stride-1272
//     layout). No wf in frame (~190 regs).
//   waves 4-7 (consumers): issue next tile's ldsB fill (async
//     global_load_lds, drains at their own barrier) + stage 2: p rows
//     [cw*16,cw*16+16) x full K=1024 against register-resident wf[32]
//     (128 regs, loaded once), QUAD independent MFMA chains (depth 8).
// One barrier per tile (was 2): stage1(t) runs concurrently with
// stage2(t-1) on each SIMD (1 producer + 1 consumer wave). Barrier counts
// provably equal (17/17); consumer tail stage2(15) after last barrier.
// launch_bounds(512,2): 8-wave block, 1 block/CU -> 2 waves/EU -> 256
// regs/wave cap -> NO spill (R6's launch_bounds(256,3) spill: 84 VGPR,
// 90 MB scratch fetch — never cap regs below wf working set).
// ---------------------------------------------------------------------------
__global__ __launch_bounds__(512, 2) void fused_opm(
    const unsigned short* __restrict__ a_b, const unsigned short* __restrict__ b_swz,
    const unsigned short* __restrict__ woT, const float* __restrict__ bo,
    float* __restrict__ out)
{
    __shared__ __align__(16) unsigned short ldsB[2][8192];      // 32 KB
    __shared__ __align__(16) unsigned short ldsM[2][16 * 1272]; // 79.5 KB

    const int b = blockIdx.x;
    const int bi = b >> 2;
    const int bj0 = (b & 3) << 4;        // 16 tiles per block
    const int wv = threadIdx.x >> 6;
    const int lane = threadIdx.x & 63;
    const int lm = lane & 15, q = lane >> 4;

    if (wv < 4) {
        // ==================== PRODUCERS: stage 1 ====================
        const int w = wv;
        short8 af[2][2];
        #pragma unroll
        for (int r = 0; r < 2; ++r)
            #pragma unroll
            for (int ks = 0; ks < 2; ++ks)
                af[r][ks] = *(const short8*)(a_b + ((size_t)(bi * 128 + w * 32 + r * 16 + lm)) * 64 + ks * 32 + q * 8);

        __syncthreads();                  // bar0: consumers' fill(0) drained

        for (int t = 0; t < 16; ++t) {
            const unsigned short* __restrict__ B = ldsB[t & 1];
            unsigned short* __restrict__ M = ldsM[t & 1];

            short8 bf[8][2];
            #pragma unroll
            for (int c = 0; c < 8; ++c)
                #pragma unroll
                for (int ks = 0; ks < 2; ++ks) {
                    const int rrow = c * 16 + lm;
                    const int o = ks * 4 + q;                   // k-octet
                    bf[c][ks] = *(const short8*)(&B[(rrow << 6) + ((o ^ (rrow & 7)) << 3)]);
                }
            float4v acc1[2][8];
            #pragma unroll
            for (int r = 0; r < 2; ++r)
                #pragma unroll
                for (int c = 0; c < 8; ++c) acc1[r][c] = (float4v){0.f, 0.f, 0.f, 0.f};
            #pragma unroll
            for (int c = 0; c < 8; ++c)
                #pragma unroll
                for (int ks = 0; ks < 2; ++ks)
                    #pragma unroll
                    for (int r = 0; r < 2; ++r)
                        acc1[r][c] = __builtin_amdgcn_mfma_f32_16x16x32_bf16(af[r][ks], bf[c][ks], acc1[r][c], 0, 0, 0);

            // C: row = w*32+r*16+q*4+e -> (i_loc=w, h), col = c*16+lm -> (j_loc=c>>1, k)
            #pragma unroll
            for (int r = 0; r < 2; ++r)
                #pragma unroll
                for (int c = 0; c < 8; ++c) {
                    const int pair = w * 4 + (c >> 1);
                    const int k = ((c & 1) << 4) + lm;
                    const int h0 = r * 16 + q * 4;
                    uint2 pk;
                    pk.x = pack2(acc1[r][c][0], acc1[r][c][1]);
                    pk.y = pack2(acc1[r][c][2], acc1[r][c][3]);
                    *(uint2*)(M + pair * 1272 + k * 40 + h0) = pk;
                }
            __syncthreads();              // bar(t+1): M[t] published
        }
        // producers exit; consumers' tail has no more barriers
    } else {
        // ==================== CONSUMERS: fills + stage 2 ====================
        const int cw = wv - 4;

        auto fill = [&](int tt) {         // async 16 KB b-tile (bj0+tt) -> ldsB[tt&1]
            #pragma unroll
            for (int li = 0; li < 4; ++li) {
                const int chunk = cw * 4 + li;                  // 16 x 1 KB chunks
                const unsigned short* g = b_swz + (size_t)(bj0 + tt) * 8192 + chunk * 512 + lane * 8;
                __builtin_amdgcn_global_load_lds((glb_u32*)g,
                    (lds_u32*)(&ldsB[tt & 1][chunk * 512]), 16, 0, 0);
            }
        };

        short8 wf[32];                    // register-resident woT: rows p = cw*16+lm
        #pragma unroll
        for (int ks = 0; ks < 32; ++ks)
            wf[ks] = *(const short8*)(woT + ((size_t)(cw * 16 + lm)) * 1024 + ks * 32 + q * 8);
        const float4 bo4 = *(const float4*)(bo + cw * 16 + q * 4);
        const int i = bi * 4 + (lm >> 2); // stage-2 pair = lm
        const int jb = lm & 3;

        auto stage2 = [&](int tt) {
            const unsigned short* __restrict__ M = ldsM[tt & 1];
            float4v a0 = (float4v){0.f, 0.f, 0.f, 0.f};
            float4v a1 = (float4v){0.f, 0.f, 0.f, 0.f};
            float4v a2 = (float4v){0.f, 0.f, 0.f, 0.f};
            float4v a3 = (float4v){0.f, 0.f, 0.f, 0.f};
            #pragma unroll
            for (int ks = 0; ks < 8; ++ks) {
                const short8 m0 = *(const short8*)(M + lm * 1272 + (4 * ks + 0) * 40 + q * 8);
                const short8 m1 = *(const short8*)(M + lm * 1272 + (4 * ks + 1) * 40 + q * 8);
                const short8 m2 = *(const short8*)(M + lm * 1272 + (4 * ks + 2) * 40 + q * 8);
                const short8 m3 = *(const short8*)(M + lm * 1272 + (4 * ks + 3) * 40 + q * 8);
                a0 = __builtin_amdgcn_mfma_f32_16x16x32_bf16(wf[4 * ks + 0], m0, a0, 0, 0, 0);
                a1 = __builtin_amdgcn_mfma_f32_16x16x32_bf16(wf[4 * ks + 1], m1, a1, 0, 0, 0);
                a2 = __builtin_amdgcn_mfma_f32_16x16x32_bf16(wf[4 * ks + 2], m2, a2, 0, 0, 0);
                a3 = __builtin_amdgcn_mfma_f32_16x16x32_bf16(wf[4 * ks + 3], m3, a3, 0, 0, 0);
            }
            const float4v sum = (a0 + a1) + (a2 + a3);
            const int j = (bj0 + tt) * 4 + jb;
            float4 o;
            o.x = sum[0] + bo4.x;
            o.y = sum[1] + bo4.y;
            o.z = sum[2] + bo4.z;
            o.w = sum[3] + bo4.w;
            *(float4*)(out + ((size_t)(i * 256 + j)) * 64 + cw * 16 + q * 4) = o;
        };

        fill(0);
        __syncthreads();                  // bar0 (own vmcnt drains fill(0))

        for (int t = 0; t < 16; ++t) {
            if (t + 1 < 16) fill(t + 1);  // B[(t+1)&1]: last read stage1(t-1); drains at bar(t+1)
            if (t >= 1) stage2(t - 1);    // M[(t-1)&1]: published at bar(t)
            __syncthreads();              // bar(t+1)
        }
        stage2(15);                       // tail, after final barrier
    }
}

// ---------------------------------------------------------------------------
extern "C" void kernel_launch(void* const* d_in, const int* in_sizes, int n_in,
                              void* d_out, int out_size, void* d_ws, size_t ws_size,
                              hipStream_t stream) {
    const float* msa  = (const float*)d_in[0];
    const float* ln_w = (const float*)d_in[1];
    const float* ln_b = (const float*)d_in[2];
    const float* wa   = (const float*)d_in[3];
    const float* ba   = (const float*)d_in[4];
    const float* wb   = (const float*)d_in[5];
    const float* bb   = (const float*)d_in[6];
    const float* wo   = (const float*)d_in[7];
    const float* bo   = (const float*)d_in[8];
    float* out = (float*)d_out;

    // workspace (bf16): a (1 MB) | b (1 MB, octet-swizzled) | woT (128 KB)
    unsigned short* a_ws = (unsigned short*)d_ws;
    unsigned short* b_ws = a_ws + 256 * 32 * 64;
    unsigned short* woT  = b_ws + 256 * 32 * 64;

    prep<<<1024, 128, 0, stream>>>(msa, ln_w, ln_b, wa, ba, wb, bb, wo, a_ws, b_ws, woT);
    fused_opm<<<256, 512, 0, stream>>>(a_ws, b_ws, woT, bo, out);
}

// Round 8
// 100.504 us; speedup vs baseline: 1.4753x; 1.0452x over previous
//
#include <hip/hip_runtime.h>
#include <hip/hip_bf16.h>

typedef __attribute__((ext_vector_type(8))) short short8;
typedef __attribute__((ext_vector_type(4))) float float4v;

typedef __attribute__((address_space(3))) unsigned int lds_u32;
typedef __attribute__((address_space(1))) const unsigned int glb_u32;

__device__ __forceinline__ unsigned short f2bf(float f) {
    // round-to-nearest-even fp32 -> bf16
    unsigned int u = __builtin_bit_cast(unsigned int, f);
    unsigned int lsb = (u >> 16) & 1u;
    u += 0x7fffu + lsb;
    return (unsigned short)(u >> 16);
}

__device__ __forceinline__ unsigned int pack2(float f0, float f1) {
    // round-half-up fp32x2 -> packed bf16x2
    unsigned int u0 = __builtin_bit_cast(unsigned int, f0) + 0x8000u;
    unsigned int u1 = __builtin_bit_cast(unsigned int, f1) + 0x8000u;
    return (u0 >> 16) | (u1 & 0xffff0000u);
}

// ---------------------------------------------------------------------------
// prep (unchanged — proven): LN + projections (MFMA) and woT build.
// b_out stored with XOR-swizzled k-octets so fused's linear global_load_lds
// yields conflict-free ds_read_b128 b-fragments.
// ---------------------------------------------------------------------------
__global__ __launch_bounds__(128) void prep(
    const float* __restrict__ msa, const float* __restrict__ ln_w,
    const float* __restrict__ ln_b, const float* __restrict__ wa,
    const float* __restrict__ ba, const float* __restrict__ wb,
    const float* __restrict__ bb, const float* __restrict__ wo,
    unsigned short* __restrict__ a_out, unsigned short* __restrict__ b_out,
    unsigned short* __restrict__ woT)
{
    const int b = blockIdx.x;
    if (b >= 512) {                       // ---- woT transpose/convert ----
        const int idx = (b - 512) * 128 + threadIdx.x;
        const int hk = idx >> 6, p = idx & 63;
        const int h = hk >> 5, k = hk & 31;
        woT[(size_t)p * 1024 + k * 32 + h] = f2bf(wo[idx]);
        return;
    }

    __shared__ __align__(16) unsigned short xn[2][16 * 72];
    const int n = b >> 1;
    const int w = threadIdx.x >> 6;
    const int lane = threadIdx.x & 63;
    const int s0 = (b & 1) * 32 + w * 16;
    const int sl = lane >> 2, dg = lane & 3;
    const int lm = lane & 15, q = lane >> 4;

    const float* __restrict__ row = msa + ((size_t)((s0 + sl) * 256 + n)) * 64;
    float4 x[4];
    #pragma unroll
    for (int ii = 0; ii < 4; ++ii) x[ii] = *(const float4*)(row + ii * 16 + dg * 4);

    float s = 0.f;
    #pragma unroll
    for (int ii = 0; ii < 4; ++ii) s += (x[ii].x + x[ii].y) + (x[ii].z + x[ii].w);
    s += __shfl_xor(s, 1, 4);
    s += __shfl_xor(s, 2, 4);
    const float mu = s * (1.f / 64.f);

    float v = 0.f;
    #pragma unroll
    for (int ii = 0; ii < 4; ++ii) {
        float a0 = x[ii].x - mu, a1 = x[ii].y - mu, a2 = x[ii].z - mu, a3 = x[ii].w - mu;
        v += (a0 * a0 + a1 * a1) + (a2 * a2 + a3 * a3);
    }
    v += __shfl_xor(v, 1, 4);
    v += __shfl_xor(v, 2, 4);
    const float rs = rsqrtf(v * (1.f / 64.f) + 1e-5f);

    #pragma unroll
    for (int ii = 0; ii < 4; ++ii) {
        const float4 lw = *(const float4*)(ln_w + ii * 16 + dg * 4);
        const float4 lb = *(const float4*)(ln_b + ii * 16 + dg * 4);
        uint2 pk;
        pk.x = pack2((x[ii].x - mu) * rs * lw.x + lb.x, (x[ii].y - mu) * rs * lw.y + lb.y);
        pk.y = pack2((x[ii].z - mu) * rs * lw.z + lb.z, (x[ii].w - mu) * rs * lw.w + lb.w);
        *(uint2*)(&xn[w][sl * 72 + ii * 16 + dg * 4]) = pk;
    }
    __syncthreads();

    short8 afr[2];
    #pragma unroll
    for (int ks = 0; ks < 2; ++ks)
        afr[ks] = *(const short8*)(&xn[w][lm * 72 + ks * 32 + q * 8]);

    float4v acc[4];
    #pragma unroll
    for (int c = 0; c < 4; ++c) acc[c] = (float4v){0.f, 0.f, 0.f, 0.f};
    #pragma unroll
    for (int c = 0; c < 4; ++c) {
        const int hp = c * 16 + lm;
        const float* __restrict__ wsrc = (hp < 32) ? (wa + hp) : (wb + hp - 32);
        #pragma unroll
        for (int ks = 0; ks < 2; ++ks) {
            short8 bfr;
            #pragma unroll
            for (int j = 0; j < 8; ++j)
                bfr[j] = (short)f2bf(wsrc[(ks * 32 + q * 8 + j) * 32]);
            acc[c] = __builtin_amdgcn_mfma_f32_16x16x32_bf16(afr[ks], bfr, acc[c], 0, 0, 0);
        }
    }

    #pragma unroll
    for (int c = 0; c < 4; ++c) {
        const int hp = c * 16 + lm;
        const float bias = (hp < 32) ? ba[hp] : bb[hp - 32];
        const float scale = (hp < 32) ? (1.f / 64.f) : 1.f;  // fold 1/S into a
        uint2 pk;
        pk.x = pack2((acc[c][0] + bias) * scale, (acc[c][1] + bias) * scale);
        pk.y = pack2((acc[c][2] + bias) * scale, (acc[c][3] + bias) * scale);
        const int sbase = s0 + q * 4;
        if (hp < 32) {
            *(uint2*)(a_out + ((size_t)(n * 32 + hp)) * 64 + sbase) = pk;
        } else {
            const int R = n * 32 + (hp - 32);
            const int o = sbase >> 3;
            const int phys = (R << 6) + (((o ^ (R & 7)) << 3) | (sbase & 7));
            *(uint2*)(b_out + phys) = pk;
        }
    }
}

// ---------------------------------------------------------------------------
// fused_opm v8: v7's producer/consumer pipeline + LDS-traffic cuts.
// v7 post-mortem: fused was at the ds_read_b128 throughput bound of its own
// traffic (240 KB/tile @ ~85 B/cyc ~= measured 20 us). v8 cuts to ~145 KB:
//   producers (waves 0-3): 2x2 tiling — wave w computes rows
//     [(w>>1)*64, +64) x cols [(w&1)*64, +64): B-reads halve (64->32 KB/tile),
//     same 32 MFMAs/wave, acc1[4][4].
//   consumers (waves 4-7): k-split x4 — wave cw contracts k in [cw*8,cw*8+8)
//     for ALL 64 p (wf[4][8], same 128 regs); M read ONCE per tile (32 KB
//     vs 128); fp32 partials -> dense double-buffered ldsR (float4,
//     conflict-free), reduced 2 tiles later by wave cw for p-tile cw.
// Uniform 18-iteration loop, one barrier per iteration, guards select work:
//   iter t: fill(t+1) | stage1(t) | stage2(t-1)->ldsR | reduce(t-2)->out.
// Buffer hazards (all 2-deep, disjoint windows): B[t] written (t-1,t), read
// (t,t+1); M[t] written (t,t+1), read (t+1,t+2); R[t] written (t+1,t+2),
// read (t+2,t+3). LDS 143.5 KB -> 1 block/CU; ~190 regs/path, no spill.
// ---------------------------------------------------------------------------
__global__ __launch_bounds__(512, 2) void fused_opm(
    const unsigned short* __restrict__ a_b, const unsigned short* __restrict__ b_swz,
    const unsigned short* __restrict__ woT, const float* __restrict__ bo,
    float* __restrict__ out)
{
    __shared__ __align__(16) unsigned short ldsB[2][8192];      // 32 KB
    __shared__ __align__(16) unsigned short ldsM[2][16 * 1272]; // 79.5 KB
    __shared__ __align__(16) float ldsR[2][4096];               // 32 KB

    const int b = blockIdx.x;
    const int bi = b >> 2;
    const int bj0 = (b & 3) << 4;        // 16 tiles per block
    const int wv = threadIdx.x >> 6;
    const int lane = threadIdx.x & 63;
    const int lm = lane & 15, q = lane >> 4;

    if (wv < 4) {
        // ==================== PRODUCERS: stage 1 (2x2 tiling) ====================
        const int wr = wv >> 1;           // row-half: i_loc in {2wr, 2wr+1}
        const int wc = wv & 1;            // col-half: j_loc in {2wc, 2wc+1}

        short8 af[4][2];                  // rows bi*128 + wr*64 + r*16 + lm
        #pragma unroll
        for (int r = 0; r < 4; ++r)
            #pragma unroll
            for (int ks = 0; ks < 2; ++ks)
                af[r][ks] = *(const short8*)(a_b + ((size_t)(bi * 128 + wr * 64 + r * 16 + lm)) * 64 + ks * 32 + q * 8);

        __syncthreads();                  // bar0: consumers' fill(0) drained

        for (int t = 0; t < 18; ++t) {
            if (t < 16) {
                const unsigned short* __restrict__ B = ldsB[t & 1];
                unsigned short* __restrict__ M = ldsM[t & 1];

                short8 bf[4][2];
                #pragma unroll
                for (int c = 0; c < 4; ++c)
                    #pragma unroll
                    for (int ks = 0; ks < 2; ++ks) {
                        const int rrow = wc * 64 + c * 16 + lm;
                        const int o = ks * 4 + q;               // k-octet
                        bf[c][ks] = *(const short8*)(&B[(rrow << 6) + ((o ^ (rrow & 7)) << 3)]);
                    }
                float4v acc1[4][4];
                #pragma unroll
                for (int r = 0; r < 4; ++r)
                    #pragma unroll
                    for (int c = 0; c < 4; ++c) acc1[r][c] = (float4v){0.f, 0.f, 0.f, 0.f};
                #pragma unroll
                for (int c = 0; c < 4; ++c)
                    #pragma unroll
                    for (int ks = 0; ks < 2; ++ks)
                        #pragma unroll
                        for (int r = 0; r < 4; ++r)
                            acc1[r][c] = __builtin_amdgcn_mfma_f32_16x16x32_bf16(af[r][ks], bf[c][ks], acc1[r][c], 0, 0, 0);

                // C row = wr*64 + r*16 + q*4+e -> i_loc = 2wr + (r>>1), h = (r&1)*16+q*4+e
                // C col = wc*64 + c*16 + lm   -> j_loc = 2wc + (c>>1), k = (c&1)*16+lm
                #pragma unroll
                for (int r = 0; r < 4; ++r)
                    #pragma unroll
                    for (int c = 0; c < 4; ++c) {
                        const int pair = (2 * wr + (r >> 1)) * 4 + 2 * wc + (c >> 1);
                        const int k = ((c & 1) << 4) + lm;
                        const int h0 = ((r & 1) << 4) + q * 4;
                        uint2 pk;
                        pk.x = pack2(acc1[r][c][0], acc1[r][c][1]);
                        pk.y = pack2(acc1[r][c][2], acc1[r][c][3]);
                        *(uint2*)(M + pair * 1272 + k * 40 + h0) = pk;
                    }
            }
            __syncthreads();              // bar(t+1)
        }
    } else {
        // ==================== CONSUMERS: fills + k-split stage 2 + reduce ====================
        const int cw = wv - 4;            // k-slice [cw*8, cw*8+8) and reduce p-tile cw

        auto fill = [&](int tt) {         // async 16 KB b-tile (bj0+tt) -> ldsB[tt&1]
            #pragma unroll
            for (int li = 0; li < 4; ++li) {
                const int chunk = cw * 4 + li;                  // 16 x 1 KB chunks
                const unsigned short* g = b_swz + (size_t)(bj0 + tt) * 8192 + chunk * 512 + lane * 8;
                __builtin_amdgcn_global_load_lds((glb_u32*)g,
                    (lds_u32*)(&ldsB[tt & 1][chunk * 512]), 16, 0, 0);
            }
        };

        short8 wf[4][8];                  // woT rows p = mt*16+lm, k = cw*8+ks
        #pragma unroll
        for (int mt = 0; mt < 4; ++mt)
            #pragma unroll
            for (int ks = 0; ks < 8; ++ks)
                wf[mt][ks] = *(const short8*)(woT + ((size_t)(mt * 16 + lm)) * 1024 + (cw * 8 + ks) * 32 + q * 8);

        const float4 bo4 = *(const float4*)(bo + cw * 16 + q * 4);
        const int i = bi * 4 + (lm >> 2);
        const int jb = lm & 3;

        fill(0);
        __syncthreads();                  // bar0

        for (int t = 0; t < 18; ++t) {
            if (t + 1 < 16) fill(t + 1);

            if (t >= 1 && t <= 16) {      // stage2(t-1): partials for tile t-1
                const int tt = t - 1;
                const unsigned short* __restrict__ M = ldsM[tt & 1];
                float4v acc2[4];
                #pragma unroll
                for (int mt = 0; mt < 4; ++mt) acc2[mt] = (float4v){0.f, 0.f, 0.f, 0.f};
                #pragma unroll
                for (int ks = 0; ks < 8; ++ks) {
                    const short8 mf = *(const short8*)(M + lm * 1272 + (cw * 8 + ks) * 40 + q * 8);
                    #pragma unroll
                    for (int mt = 0; mt < 4; ++mt)
                        acc2[mt] = __builtin_amdgcn_mfma_f32_16x16x32_bf16(wf[mt][ks], mf, acc2[mt], 0, 0, 0);
                }
                float* __restrict__ R = ldsR[tt & 1];
                #pragma unroll
                for (int mt = 0; mt < 4; ++mt)
                    *(float4v*)(&R[((cw * 4 + mt) << 8) + (lane << 2)]) = acc2[mt];
            }

            if (t >= 2) {                 // reduce(t-2): p-tile cw, all k-slices
                const int tt = t - 2;
                const float* __restrict__ R = ldsR[tt & 1];
                float4v sum = *(const float4v*)(&R[(cw << 8) + (lane << 2)]);
                #pragma unroll
                for (int kh = 1; kh < 4; ++kh)
                    sum += *(const float4v*)(&R[((kh * 4 + cw) << 8) + (lane << 2)]);
                const int j = (bj0 + tt) * 4 + jb;
                float4 o;
                o.x = sum[0] + bo4.x;
                o.y = sum[1] + bo4.y;
                o.z = sum[2] + bo4.z;
                o.w = sum[3] + bo4.w;
                *(float4*)(out + ((size_t)(i * 256 + j)) * 64 + cw * 16 + q * 4) = o;
            }
            __syncthreads();              // bar(t+1)
        }
    }
}

// ---------------------------------------------------------------------------
extern "C" void kernel_launch(void* const* d_in, const int* in_sizes, int n_in,
                              void* d_out, int out_size, void* d_ws, size_t ws_size,
                              hipStream_t stream) {
    const float* msa  = (const float*)d_in[0];
    const float* ln_w = (const float*)d_in[1];
    const float* ln_b = (const float*)d_in[2];
    const float* wa   = (const float*)d_in[3];
    const float* ba   = (const float*)d_in[4];
    const float* wb   = (const float*)d_in[5];
    const float* bb   = (const float*)d_in[6];
    const float* wo   = (const float*)d_in[7];
    const float* bo   = (const float*)d_in[8];
    float* out = (float*)d_out;

    // workspace (bf16): a (1 MB) | b (1 MB, octet-swizzled) | woT (128 KB)
    unsigned short* a_ws = (unsigned short*)d_ws;
    unsigned short* b_ws = a_ws + 256 * 32 * 64;
    unsigned short* woT  = b_ws + 256 * 32 * 64;

    prep<<<1024, 128, 0, stream>>>(msa, ln_w, ln_b, wa, ba, wb, bb, wo, a_ws, b_ws, woT);
    fused_opm<<<256, 512, 0, stream>>>(a_ws, b_ws, woT, bo, out);
}